// Round 5
// baseline (553.475 us; speedup 1.0000x reference)
//
#include <hip/hip_runtime.h>
#include <hip/hip_bf16.h>

// Problem constants
#define NNEUR 8192
#define NCONV 64
#define LYC   36
#define LXC   36
#define BATCH 256
#define KRAW  1296   // 36*36
#define KITER 42     // K padded to 42*32 = 1344
#define BK    32
#define MROWS 16384  // BATCH*NCONV
#define BM 256
#define BN 256
// k-major staged layout: per (tile, iter): 4 chunk-regions (c = k-subblock of
// 8 halfs), each 256 rows x 8 halfs. Chunk idx in [0,1024): c = idx>>8,
// r = idx&255. One chunk = 16 B.
#define CH_IT 1024
#define TILE_H (KITER * CH_IT * 8)  // 344064 halfs per (m- or n-) tile
#define A_NTILES 64
#define B_NTILES 32
#define A_PREP_BLOCKS (A_NTILES * KITER)  // 2688
#define B_PREP_BLOCKS (B_NTILES * KITER)  // 1344

typedef __attribute__((ext_vector_type(8))) _Float16 half8;
typedef __attribute__((ext_vector_type(4))) float f32x4;
typedef __attribute__((ext_vector_type(16))) float f32x16;

__device__ __forceinline__ void async_copy16(const void* g, void* l) {
  __builtin_amdgcn_global_load_lds(
      (const __attribute__((address_space(1))) void*)g,
      (__attribute__((address_space(3))) void*)l, 16, 0, 0);
}

// Prep: A = conv->f16, B = Wy*Wx*256->f16, both emitted k-major (chunk-major
// within each BK=32 iter) so GEMM staging and fragment reads are contiguous.
// A path: coalesced float4 loads -> LDS transpose -> contiguous half8 stores.
__global__ __launch_bounds__(256) void prep_kernel(
    const float* __restrict__ conv, const float* __restrict__ Wy,
    const float* __restrict__ Wx, _Float16* __restrict__ A,
    _Float16* __restrict__ B) {
  const int t = threadIdx.x;
  if (blockIdx.x < A_PREP_BLOCKS) {  // ---- A: one block per (mtile, iter)
    const int tile = blockIdx.x / KITER;
    const int it = blockIdx.x - tile * KITER;
    __shared__ _Float16 sm[256 * 40];  // rows padded to 40 halfs (80 B)
#pragma unroll
    for (int i = 0; i < 8; i++) {      // load 256 rows x 8 float4 (32 floats)
      const int idx = i * 256 + t;
      const int r = idx >> 3, j = idx & 7;
      const int k0 = it * BK + j * 4;
      float4 f = make_float4(0.f, 0.f, 0.f, 0.f);
      if (k0 + 3 < KRAW)  // KRAW % 4 == 0: float4 never straddles the edge
        f = *(const float4*)(conv + (size_t)(tile * BM + r) * KRAW + k0);
      _Float16* d = sm + r * 40 + j * 4;
      d[0] = (_Float16)f.x; d[1] = (_Float16)f.y;
      d[2] = (_Float16)f.z; d[3] = (_Float16)f.w;
    }
    __syncthreads();
#pragma unroll
    for (int i = 0; i < 4; i++) {      // store 1024 chunks, chunk-major
      const int idx = i * 256 + t;
      const int c = idx >> 8, r = idx & 255;
      const _Float16* s = sm + r * 40 + c * 8;
      half8 h;
#pragma unroll
      for (int e = 0; e < 8; e++) h[e] = s[e];
      *(half8*)(A + (size_t)tile * TILE_H + (size_t)it * (CH_IT * 8) +
                (size_t)idx * 8) = h;
    }
  } else {  // ---- B: one block per (ntile, iter), computed directly
    const int b = blockIdx.x - A_PREP_BLOCKS;
    const int tile = b / KITER;
    const int it = b - tile * KITER;
#pragma unroll
    for (int i = 0; i < 4; i++) {
      const int idx = i * 256 + t;
      const int c = idx >> 8, r = idx & 255;
      const int n = tile * BN + r;
      const int k0 = it * BK + c * 8;
      half8 h;
#pragma unroll
      for (int e = 0; e < 8; e++) {
        const int k = k0 + e;
        float v = 0.f;
        if (k < KRAW) {
          const int y = k / LXC;
          const int x = k - y * LXC;
          v = Wy[n * LYC + y] * Wx[n * LXC + x] * 256.f;
        }
        h[e] = (_Float16)v;
      }
      *(half8*)(B + (size_t)tile * TILE_H + (size_t)it * (CH_IT * 8) +
                (size_t)idx * 8) = h;
    }
  }
}

// Fused GEMM: block 256x256, 4 waves (2x2), wave-tile 128x128 with 32x32x16
// f16 MFMA (acc[4][4] f32x16 = 256 AGPR, 1 wave/SIMD). BK=32, double-buffered
// 2x32 KB LDS, ONE barrier per iter: DMA for it+1 issued after the barrier,
// in flight during compute on it, drained by the next barrier. k-major LDS:
// fragment reads are contiguous 512 B per half-wave (conflict-free).
__global__ __launch_bounds__(256, 1) void gemm_fused_kernel(
    const _Float16* __restrict__ A, const _Float16* __restrict__ B,
    const float* __restrict__ Wc, const float* __restrict__ bias,
    float* __restrict__ out) {
  __shared__ _Float16 lds[2][(BM + BN) * BK];  // 2 x 32 KB

  // XCD swizzle: xcd = bid&7 owns 4 n-tiles (B panel 2.75 MB, L2-resident);
  // 4 consecutive blocks per XCD share one A-tile.
  const int bid = blockIdx.x;  // 0..2047
  const int l = bid >> 3;
  const int ntile = (bid & 7) * 4 + (l & 3);  // 0..31
  const int mtile = l >> 2;                   // 0..63

  const int t = threadIdx.x;
  const int lane = t & 63;
  const int wave = t >> 6;                  // 0..3
  const int wm = wave >> 1, wn = wave & 1;  // 2x2; wave tile 128x128
  const int r32 = lane & 31, hh = lane >> 5;

  f32x16 acc[4][4] = {};  // [mb][nb]

  const _Float16* pA = A + (size_t)mtile * TILE_H + t * 8;
  const _Float16* pB = B + (size_t)ntile * TILE_H + t * 8;

  // Prologue: stage iter 0 into buffer 0.
#pragma unroll
  for (int i = 0; i < 4; i++)
    async_copy16(pA + i * 2048, &lds[0][0] + t * 8 + i * 2048);
#pragma unroll
  for (int i = 0; i < 4; i++)
    async_copy16(pB + i * 2048, &lds[0][BM * BK] + t * 8 + i * 2048);

  int cur = 0;
  for (int it = 0; it < KITER; ++it) {
    __syncthreads();  // completes DMA for buf[cur]; drains prev-iter DMA late
    if (it + 1 < KITER) {
      const _Float16* nA = pA + (size_t)(it + 1) * (CH_IT * 8);
      const _Float16* nB = pB + (size_t)(it + 1) * (CH_IT * 8);
      _Float16* dA = &lds[cur ^ 1][0] + t * 8;
      _Float16* dB = &lds[cur ^ 1][BM * BK] + t * 8;
#pragma unroll
      for (int i = 0; i < 4; i++) async_copy16(nA + i * 2048, dA + i * 2048);
#pragma unroll
      for (int i = 0; i < 4; i++) async_copy16(nB + i * 2048, dB + i * 2048);
    }
    const _Float16* As_ = &lds[cur][0];
    const _Float16* Bs_ = &lds[cur][BM * BK];
#pragma unroll
    for (int ks = 0; ks < 2; ++ks) {
      const int cc = 2 * ks + hh;  // k-subblock for this lane-half
      half8 af[4], bf[4];
#pragma unroll
      for (int mb = 0; mb < 4; mb++)
        af[mb] = *(const half8*)(As_ + cc * 2048 + (wm * 128 + mb * 32 + r32) * 8);
#pragma unroll
      for (int nb = 0; nb < 4; nb++)
        bf[nb] = *(const half8*)(Bs_ + cc * 2048 + (wn * 128 + nb * 32 + r32) * 8);
#pragma unroll
      for (int mb = 0; mb < 4; mb++)
#pragma unroll
        for (int nb = 0; nb < 4; nb++)
          acc[mb][nb] = __builtin_amdgcn_mfma_f32_32x32x16_f16(
              af[mb], bf[nb], acc[mb][nb], 0, 0, 0);
    }
    cur ^= 1;
  }

  // Epilogue. C/D 32x32: col = lane&31, row = (reg&3)+8*(reg>>2)+4*hh.
  // Wave's 128 M-rows = 2 images x 64 channels; mb 0,1 -> img0, mb 2,3 -> img1.
  const int ibase = mtile * 4 + wm * 2;
  float v[2][4];  // [img][nb]
#pragma unroll
  for (int nb = 0; nb < 4; nb++) {
    const int n_g = ntile * BN + wn * 128 + nb * 32 + r32;
    const float* wc = Wc + (size_t)n_g * NCONV;
    f32x4 w[2][4];
#pragma unroll
    for (int hf = 0; hf < 2; hf++)
#pragma unroll
      for (int g = 0; g < 4; g++)
        w[hf][g] = *(const f32x4*)(wc + hf * 32 + hh * 4 + g * 8);
#pragma unroll
    for (int img = 0; img < 2; img++) {
      float p = 0.f;
#pragma unroll
      for (int hf = 0; hf < 2; hf++)
#pragma unroll
        for (int g = 0; g < 4; g++)
#pragma unroll
          for (int q = 0; q < 4; q++)
            p += acc[img * 2 + hf][nb][g * 4 + q] * w[hf][g][q];
      p += __shfl_xor(p, 32);  // combine the two row-halves
      v[img][nb] = p;
    }
  }
  const int img = ibase + hh;  // lane writes its own half's image
#pragma unroll
  for (int nb = 0; nb < 4; nb++) {
    const int n_out = ntile * BN + wn * 128 + nb * 32 + r32;
    float z = v[hh][nb] * 0.00390625f + bias[n_out];  // undo x256 scaling
    z = z > 0.f ? z : (__expf(z) - 1.f);
    out[(size_t)img * NNEUR + n_out] = z;
  }
}

extern "C" void kernel_launch(void* const* d_in, const int* in_sizes, int n_in,
                              void* d_out, int out_size, void* d_ws,
                              size_t ws_size, hipStream_t stream) {
  const float* conv = (const float*)d_in[0];
  const float* Wc = (const float*)d_in[1];
  const float* Wy = (const float*)d_in[2];
  const float* Wx = (const float*)d_in[3];
  const float* bias = (const float*)d_in[4];
  float* out = (float*)d_out;

  _Float16* Abuf = (_Float16*)d_ws;  // 64 tiles * 344064 halfs = 44.0 MB
  _Float16* Bbuf =
      (_Float16*)((char*)d_ws + (size_t)A_NTILES * TILE_H * 2);  // 22.0 MB

  prep_kernel<<<A_PREP_BLOCKS + B_PREP_BLOCKS, 256, 0, stream>>>(conv, Wy, Wx,
                                                                 Abuf, Bbuf);
  gemm_fused_kernel<<<2048, 256, 0, stream>>>(Abuf, Bbuf, Wc, bias, out);
}